// Round 18
// baseline (290.656 us; speedup 1.0000x reference)
//
#include <hip/hip_runtime.h>
#include <hip/hip_bf16.h>
#include <stdint.h>

// Problem constants
#define S2   2048
#define DD   4096
#define NH   32
#define NKVH 8
#define HD2  128
// qkv buffer row width: 4096 (q) + 1024 (k) + 1024 (v; written to Vt instead)
#define QKVW 6144

typedef __bf16 bf16x8 __attribute__((ext_vector_type(8)));
typedef float  f32x4  __attribute__((ext_vector_type(4)));
typedef unsigned short u16x8 __attribute__((ext_vector_type(8)));
typedef unsigned short u16x4 __attribute__((ext_vector_type(4)));

__device__ __forceinline__ unsigned short f2b(float f) {
    unsigned int u = __builtin_bit_cast(unsigned int, f);
    unsigned int r = (u + 0x7FFFu + ((u >> 16) & 1u)) >> 16;   // RNE
    return (unsigned short)r;
}
__device__ __forceinline__ float b2f(unsigned short h) {
    unsigned int u = ((unsigned int)h) << 16;
    return __builtin_bit_cast(float, u);
}
__device__ __forceinline__ unsigned cvt_pk_bf16(float a, float b) {
    unsigned r;
    asm("v_cvt_pk_bf16_f32 %0, %1, %2" : "=v"(r) : "v"(a), "v"(b));
    return r;   // lo16 = bf16(a), hi16 = bf16(b)
}

// global -> LDS direct copy, 16B per lane. LDS dest is wave-uniform base + lane*16.
__device__ __forceinline__ void gload_lds16(const void* g, void* lds) {
    __builtin_amdgcn_global_load_lds(
        (const __attribute__((address_space(1))) void*)(uintptr_t)g,
        (__attribute__((address_space(3))) void*)(uint32_t)(uintptr_t)lds,
        16, 0, 0);
}

// raw barrier (no vmcnt drain) + compiler memory fences so LDS ops don't cross
#define BAR() do { asm volatile("" ::: "memory"); \
                   __builtin_amdgcn_s_barrier();  \
                   asm volatile("" ::: "memory"); } while (0)
#define WAITV(n) asm volatile("s_waitcnt vmcnt(" #n ")" ::: "memory")

template<int N> __device__ __forceinline__ void waitv() {
    if      constexpr (N == 0)  WAITV(0);
    else if constexpr (N == 1)  WAITV(1);
    else if constexpr (N == 2)  WAITV(2);
    else if constexpr (N == 3)  WAITV(3);
    else if constexpr (N == 4)  WAITV(4);
    else if constexpr (N == 5)  WAITV(5);
    else if constexpr (N == 6)  WAITV(6);
    else if constexpr (N == 8)  WAITV(8);
}

// ---------------------------------------------------------------------------
// 1) fp32 -> bf16 conversion for x, wq, wk, wv (wo is converted inside attn)
// ---------------------------------------------------------------------------
__global__ void cvt_all(const float* __restrict__ x,  const float* __restrict__ wq,
                        const float* __restrict__ wk, const float* __restrict__ wv,
                        unsigned short* __restrict__ dst) {
    const long long NG = 8LL * 1024 * 1024;   // float4 groups (x 2M | wq 4M | wk 1M | wv 1M)
    const long long stride = (long long)gridDim.x * blockDim.x;
    for (long long g = (long long)blockIdx.x * blockDim.x + threadIdx.x; g < NG; g += stride) {
        const float* src; long long off;
        if      (g < 2LL*1024*1024) { src = x;  off = g; }
        else if (g < 6LL*1024*1024) { src = wq; off = g - 2LL*1024*1024; }
        else if (g < 7LL*1024*1024) { src = wk; off = g - 6LL*1024*1024; }
        else                        { src = wv; off = g - 7LL*1024*1024; }
        f32x4 v = *reinterpret_cast<const f32x4*>(src + off * 4);
        u16x4 o;
        o[0] = f2b(v[0]); o[1] = f2b(v[1]); o[2] = f2b(v[2]); o[3] = f2b(v[3]);
        *reinterpret_cast<u16x4*>(dst + g * 4) = o;
    }
}

// ---------------------------------------------------------------------------
// 2) QKV GEMM  qkv[2048 x 6144] = x * [wq|wk|wv]^T, with FUSED RoPE epilogue
//    and V written transposed to Vt (replaces the rope_tv kernel).
//    r17 2-barrier-per-tile schedule unchanged. BM=256, BN=192, BK=64,
//    grid (32,8) = 256 blocks, 8 waves 4M x 2N.
//    Epilogue: cols<5120 -> RoPE pairs live in adjacent lanes (col = ...+r16),
//    so partner value comes from __shfl_xor(v,1); Q cols additionally scaled
//    by log2(e)/sqrt(HD). Rope applied in fp32 pre-rounding (slightly more
//    accurate than the old bf16->rope->bf16 path). Cols>=5120 (V) -> write
//    Vt[kvh][d][row] (4 consecutive rows per lane = aligned 8B store); V is
//    never written to qkv (nothing reads it there).
// ---------------------------------------------------------------------------
__global__ __launch_bounds__(512) void gemm_qkv(
    const unsigned short* __restrict__ A,    // xb  [2048 x 4096]
    const unsigned short* __restrict__ B0,   // wq  [4096 x 4096]
    const unsigned short* __restrict__ B1,   // wk  [1024 x 4096]
    const unsigned short* __restrict__ B2,   // wv  [1024 x 4096]
    unsigned short* __restrict__ C,          // qkv [2048 x 6144]
    const float* __restrict__ fc,            // cos [2048 x 64]
    const float* __restrict__ fs,            // sin [2048 x 64]
    unsigned short* __restrict__ Vt)         // [8][128][2048]
{
    constexpr int K = 4096, BK = 64, NT = K / BK;
    __shared__ unsigned short As[2][256 * 64];   // 64 KB
    __shared__ unsigned short Bs[2][192 * 64];   // 48 KB

    const int bm = blockIdx.y, bn = blockIdx.x;  // (32, 8): lin%8 == bn%8
    const int tid = threadIdx.x;
    const int w = tid >> 6, lane = tid & 63;
    const int wr = w >> 1, wc = w & 1;           // 4M x 2N
    const int r16 = lane & 15, g4 = lane >> 4;

    const int bn0 = bn * 192;
    const unsigned short* Ap = A + (size_t)bm * 256 * K;

    const int lrow = lane >> 3;   // 0..7 (row within 8-row unit)
    const int lchk = lane & 7;    // 0..7 (16B chunk within 128B row)

    f32x4 acc[4][6] = {};
    bf16x8 af[4][2], b0[3][2], b1[3][2];

    auto browbase = [&](int rowg) -> const unsigned short* {
        if (rowg < 4096) return B0 + (size_t)rowg * K;
        if (rowg < 5120) return B1 + (size_t)(rowg - 4096) * K;
        return B2 + (size_t)(rowg - 5120) * K;
    };

    auto stageA = [&](int buf, int tt, int half) {
        #pragma unroll
        for (int i = 0; i < 2; ++i) {
            const int j = i * 8 + w;                               // unit 0..15
            const int row0 = (j >> 2) * 64 + half * 32 + (j & 3) * 8;
            const int row = row0 + lrow;
            gload_lds16(Ap + (size_t)row * K + tt * BK + ((lchk ^ (row & 7)) * 8),
                        &As[buf][row0 * 64]);
        }
    };
    auto stageB = [&](int buf, int tt, int half) {
        #pragma unroll
        for (int i = 0; i < 2; ++i) {
            const int j = (i == 0) ? w : (8 + (w & 3));            // unit 0..11
            const int row0 = (j < 6) ? (half * 48 + j * 8)
                                     : (96 + half * 48 + (j - 6) * 8);
            const int row = row0 + lrow;
            const unsigned short* src = browbase(bn0 + row0) + (size_t)lrow * K;
            gload_lds16(src + tt * BK + ((lchk ^ (row & 7)) * 8),
                        &Bs[buf][row0 * 64]);
        }
    };
    auto readA = [&](int buf, int mh) {
        #pragma unroll
        for (int m = 0; m < 2; ++m)
            #pragma unroll
            for (int kk = 0; kk < 2; ++kk) {
                const int row = wr * 64 + mh * 32 + m * 16 + r16;
                af[mh * 2 + m][kk] = *reinterpret_cast<const bf16x8*>(
                    &As[buf][row * 64 + (((kk * 4 + g4) ^ (row & 7)) * 8)]);
            }
    };
    auto readB = [&](int buf, int nh, bf16x8 (&br)[3][2]) {
        #pragma unroll
        for (int n = 0; n < 3; ++n)
            #pragma unroll
            for (int kk = 0; kk < 2; ++kk) {
                const int row = wc * 96 + nh * 48 + n * 16 + r16;
                br[n][kk] = *reinterpret_cast<const bf16x8*>(
                    &Bs[buf][row * 64 + (((kk * 4 + g4) ^ (row & 7)) * 8)]);
            }
    };
    auto mma = [&](bf16x8 (&br)[3][2], int nh) {   // all 4 m-frags x 3 n-frags
        __builtin_amdgcn_s_setprio(1);
        #pragma unroll
        for (int m = 0; m < 4; ++m)
            #pragma unroll
            for (int n = 0; n < 3; ++n)
                #pragma unroll
                for (int kk = 0; kk < 2; ++kk)
                    acc[m][nh * 3 + n] = __builtin_amdgcn_mfma_f32_16x16x32_bf16(
                        af[m][kk], br[n][kk], acc[m][nh * 3 + n], 0, 0, 0);
        __builtin_amdgcn_s_setprio(0);
    };

    // prologue: stage tile 0 fully, drain
    stageA(0, 0, 0); stageA(0, 0, 1); stageB(0, 0, 0); stageB(0, 0, 1);
    waitv<0>();
    BAR();

    for (int t = 0; t < NT - 1; ++t) {
        const int buf = t & 1;
        // ---- phase 0: all-m x n-half0 ----
        readA(buf, 0); readA(buf, 1); readB(buf, 0, b0);
        stageA(buf ^ 1, t + 1, 0); stageA(buf ^ 1, t + 1, 1); stageB(buf ^ 1, t + 1, 0);
        mma(b0, 0);
        waitv<6>();                 // lands B-h1(t); leaves A0',A1',B0'(t+1)
        BAR();
        // ---- phase 1: all-m x n-half1 ----
        readB(buf, 1, b1);
        stageB(buf ^ 1, t + 1, 1);
        mma(b1, 1);
        waitv<2>();                 // lands A0',A1',B0'(t+1); leaves B1'(t+1)
        BAR();
    }
    // ---- last tile (no staging) ----
    {
        const int buf = (NT - 1) & 1;
        readA(buf, 0); readA(buf, 1); readB(buf, 0, b0);
        mma(b0, 0);
        waitv<0>();                 // B-h1 landed (was left in flight)
        BAR();
        readB(buf, 1, b1);
        mma(b1, 1);
    }

    // ---- epilogue: fused RoPE (Q scaled) + V -> Vt transpose ----
    constexpr float QSCALE = 0.08838834764831845f * 1.4426950408889634f; // 1/sqrt(128)*log2(e)
    const int crow0 = bm * 256 + wr * 64;
    const int ccol0 = bn0 + wc * 96;
    #pragma unroll
    for (int m = 0; m < 4; ++m)
        #pragma unroll
        for (int n = 0; n < 6; ++n) {
            const int col = ccol0 + n * 16 + r16;
            if (col < 5120) {                          // Q or K: rope (wave-uniform branch)
                const int i0 = (col & 127) >> 1;
                const float post = (col < 4096) ? QSCALE : 1.0f;
                const bool ev = (col & 1) == 0;
                #pragma unroll
                for (int r = 0; r < 4; ++r) {
                    const int row = crow0 + m * 16 + g4 * 4 + r;
                    const float v  = acc[m][n][r];
                    const float pv = __shfl_xor(v, 1);     // partner column value
                    const float cc = fc[row * 64 + i0];
                    const float ss = fs[row * 64 + i0];
                    const float ov = ev ? (v * cc - pv * ss) : (pv * ss + v * cc);
                    C[(size_t)row * QKVW + col] = f2b(ov * post);
                }
            } else {                                   // V: transposed into Vt
                const int dl  = col - 5120;            // 0..1023
                const int kvh = dl >> 7, d = dl & 127;
                const int row0 = crow0 + m * 16 + g4 * 4;
                u16x4 vv;
                #pragma unroll
                for (int r = 0; r < 4; ++r) vv[r] = f2b(acc[m][n][r]);
                *reinterpret_cast<u16x4*>(
                    Vt + (size_t)kvh * HD2 * S2 + (size_t)d * S2 + row0) = vv;
            }
        }
}

// ---------------------------------------------------------------------------
// 2b) O-proj GEMM  out[2048 x 4096] = ob * wo^T.  (r17 2-barrier, unchanged)
// ---------------------------------------------------------------------------
__global__ __launch_bounds__(512) void gemm_out(
    const unsigned short* __restrict__ A,   // ob  [2048 x 4096] bf16
    const unsigned short* __restrict__ B,   // wob [4096 x 4096] bf16
    float* __restrict__ C)                  // out [2048 x 4096] f32
{
    constexpr int K = 4096, BK = 64, NT = K / BK;
    __shared__ unsigned short As[2][128 * 64];   // 32 KB
    __shared__ unsigned short Bs[2][256 * 64];   // 64 KB

    const int bm = blockIdx.y, bn = blockIdx.x;  // (16, 16): lin%8 == bn%8
    const int tid = threadIdx.x;
    const int w = tid >> 6, lane = tid & 63;
    const int wr = w >> 2, wc = w & 3;           // 2M x 4N
    const int r16 = lane & 15, g4 = lane >> 4;

    const unsigned short* Ap = A + (size_t)bm * 128 * K;
    const unsigned short* Bp = B + (size_t)bn * 256 * K;

    const int lrow = lane >> 3;
    const int lchk = lane & 7;

    f32x4 acc[4][4] = {};
    bf16x8 af[4][2], b0[2][2], b1[2][2];

    auto stageA = [&](int buf, int tt, int half) {
        const int j = w;                                           // unit 0..7
        const int row0 = (j >> 2) * 64 + half * 32 + (j & 3) * 8;
        const int row = row0 + lrow;
        gload_lds16(Ap + (size_t)row * K + tt * BK + ((lchk ^ (row & 7)) * 8),
                    &As[buf][row0 * 64]);
    };
    auto stageB = [&](int buf, int tt, int half) {
        #pragma unroll
        for (int i = 0; i < 2; ++i) {
            const int j = i * 8 + w;                               // unit 0..15
            const int row0 = (j >> 2) * 64 + half * 32 + (j & 3) * 8;
            const int row = row0 + lrow;
            gload_lds16(Bp + (size_t)row * K + tt * BK + ((lchk ^ (row & 7)) * 8),
                        &Bs[buf][row0 * 64]);
        }
    };
    auto readA = [&](int buf, int mh) {
        #pragma unroll
        for (int m = 0; m < 2; ++m)
            #pragma unroll
            for (int kk = 0; kk < 2; ++kk) {
                const int row = wr * 64 + mh * 32 + m * 16 + r16;
                af[mh * 2 + m][kk] = *reinterpret_cast<const bf16x8*>(
                    &As[buf][row * 64 + (((kk * 4 + g4) ^ (row & 7)) * 8)]);
            }
    };
    auto readB = [&](int buf, int nh, bf16x8 (&br)[2][2]) {
        #pragma unroll
        for (int n = 0; n < 2; ++n)
            #pragma unroll
            for (int kk = 0; kk < 2; ++kk) {
                const int row = wc * 64 + nh * 32 + n * 16 + r16;
                br[n][kk] = *reinterpret_cast<const bf16x8*>(
                    &Bs[buf][row * 64 + (((kk * 4 + g4) ^ (row & 7)) * 8)]);
            }
    };
    auto mma = [&](bf16x8 (&br)[2][2], int nh) {   // all 4 m-frags x 2 n-frags
        __builtin_amdgcn_s_setprio(1);
        #pragma unroll
        for (int m = 0; m < 4; ++m)
            #pragma unroll
            for (int n = 0; n < 2; ++n)
                #pragma unroll
                for (int kk = 0; kk < 2; ++kk)
                    acc[m][nh * 2 + n] = __builtin_amdgcn_mfma_f32_16x16x32_bf16(
                        af[m][kk], br[n][kk], acc[m][nh * 2 + n], 0, 0, 0);
        __builtin_amdgcn_s_setprio(0);
    };

    stageA(0, 0, 0); stageA(0, 0, 1); stageB(0, 0, 0); stageB(0, 0, 1);
    waitv<0>();
    BAR();

    for (int t = 0; t < NT - 1; ++t) {
        const int buf = t & 1;
        // ---- phase 0 ----
        readA(buf, 0); readA(buf, 1); readB(buf, 0, b0);
        stageA(buf ^ 1, t + 1, 0); stageA(buf ^ 1, t + 1, 1); stageB(buf ^ 1, t + 1, 0);
        mma(b0, 0);
        waitv<4>();                 // lands B-h1(t); leaves A0',A1',B0'(t+1)
        BAR();
        // ---- phase 1 ----
        readB(buf, 1, b1);
        stageB(buf ^ 1, t + 1, 1);
        mma(b1, 1);
        waitv<2>();                 // lands A0',A1',B0'(t+1); leaves B1'(t+1)
        BAR();
    }
    {
        const int buf = (NT - 1) & 1;
        readA(buf, 0); readA(buf, 1); readB(buf, 0, b0);
        mma(b0, 0);
        waitv<0>();
        BAR();
        readB(buf, 1, b1);
        mma(b1, 1);
    }

    const size_t crow0 = (size_t)bm * 128 + wr * 64;
    const size_t ccol0 = (size_t)bn * 256 + wc * 64;
    #pragma unroll
    for (int m = 0; m < 4; ++m)
        #pragma unroll
        for (int n = 0; n < 4; ++n)
            #pragma unroll
            for (int r = 0; r < 4; ++r)
                C[(crow0 + m * 16 + g4 * 4 + r) * DD + ccol0 + n * 16 + r16] = acc[m][n][r];
}

// ---------------------------------------------------------------------------
// 5) Flash attention (r12 body) + wo fp32->bf16 side-job with BATCHED flush.
//    r17 lesson: per-tile WAITV(0) drains also wait for the side-job's global
//    STORES to retire (~500+ cyc each occurrence). Stores now flushed 8-at-a-
//    time every 4th tile (4 store-drain events instead of 16); loads still
//    issued 2/tile (fully latency-hidden). cbuf grows to 8 x f32x4.
// ---------------------------------------------------------------------------
__global__ __launch_bounds__(512) void attn_kernel(const unsigned short* __restrict__ Qkv,
                                                   const unsigned short* __restrict__ Vt,
                                                   unsigned short* __restrict__ O,
                                                   const float* __restrict__ wo_src,
                                                   unsigned short* __restrict__ wo_dst) {
    __shared__ unsigned short Klds[2][64 * 128];   // 32 KB
    __shared__ unsigned short Vlds[2][128 * 64];   // 32 KB
    __shared__ unsigned short Plds[8][2048];       // 32 KB (4 KB/wave, frag-ordered)

    const int kvh = blockIdx.x;                  // 0..7
    const int h   = kvh * 4 + (blockIdx.y & 3);
    const int p   = blockIdx.y >> 2;             // pair id 0..7
    const int cB  = 8 + p, cS = 7 - p;           // complement chunks
    const int w = threadIdx.x >> 6, lane = threadIdx.x & 63;
    const int tid = threadIdx.x;
    const int r16 = lane & 15, g4 = lane >> 4;

    const int myc = (w < 4) ? cB : cS;
    const int qw  = myc * 128 + (w & 3) * 32;    // wave's first q row
    const int ntB = 2 * cB + 2;                  // tiles staged by this block (>= 18)

    const unsigned short* Kbase = Qkv + DD + kvh * HD2;      // + kv*QKVW + d
    const unsigned short* Vtb   = Vt + (size_t)kvh * HD2 * S2;
    char* pw = (char*)(&Plds[w][0]);             // wave's 4KB P region

    // wo conversion side-job: block blk covers 16384 f32x4 groups.
    // 16 batches x 2 f32x4; issue batch k at tile k; flush batches 4-at-a-time
    // at tiles 4,8,12,16 (stores batched -> 4 store-drain events, not 16).
    const int blk = blockIdx.y * 8 + blockIdx.x;           // 0..255
    const f32x4* wo4 = (const f32x4*)wo_src;
    const int cb4 = blk * 16384 + tid;
    f32x4 cbuf[8];
    auto cvt_issue = [&](int k) {
        #pragma unroll
        for (int i = 0; i < 2; ++i)
            cbuf[(k & 3) * 2 + i] = wo4[cb4 + k * 1024 + i * 512];
    };
    auto cvt_flush4 = [&](int k0) {
        #pragma unroll
        for (int k = 0; k < 4; ++k)
            #pragma unroll
            for (int i = 0; i < 2; ++i) {
                const f32x4 vsrc = cbuf[((k0 + k) & 3) * 2 + i];
                u16x4 ov;
                ov[0] = f2b(vsrc[0]); ov[1] = f2b(vsrc[1]);
                ov[2] = f2b(vsrc[2]); ov[3] = f2b(vsrc[3]);
                *reinterpret_cast<u16x4*>(
                    wo_dst + ((size_t)(cb4 + (k0 + k) * 1024 + i * 512)) * 4) = ov;
            }
    };

    // staging lane constants
    const int krow_l = lane >> 4;      // row within 4-row segment
    const int kchunk = lane & 15;      // 16B chunk within 256B K row
    const int vd_l   = lane >> 3;      // d within 8-row segment
    const int vchunk = lane & 7;       // 16B chunk within 128B V row

    // Q fragments (B-frag of swapped QK^T): rows qw+m*16+r16, d-slices f*32+g4*8
    bf16x8 qf[2][4];
    #pragma unroll
    for (int m = 0; m < 2; ++m)
        #pragma unroll
        for (int f = 0; f < 4; ++f)
            qf[m][f] = *reinterpret_cast<const bf16x8*>(
                Qkv + (size_t)(qw + m * 16 + r16) * QKVW + h * HD2 + f * 32 + g4 * 8);

    f32x4 o[2][8] = {};
    float mr[2] = {-3e38f, -3e38f};   // running max (log2 units) for q = m*16+r16
    float lr[2] = {0.f, 0.f};

    auto stage = [&](int buf, int kv0) {
        #pragma unroll
        for (int i = 0; i < 2; ++i) {
            const int seg = i * 8 + w;                     // 0..15
            const int row = seg * 4 + krow_l;              // kv row 0..63
            gload_lds16(Kbase + (size_t)(kv0 + row) * QKVW + ((kchunk ^ (row & 7)) * 8),
                        &Klds[buf][seg * 512]);
        }
        #pragma unroll
        for (int i = 0; i < 2; ++i) {
            const int seg = i * 8 + w;
            const int d = seg * 8 + vd_l;                  // d row 0..127
            gload_lds16(Vtb + (size_t)d * S2 + kv0 + ((vchunk ^ (d & 7)) * 8),
                        &Vlds[buf][seg * 512]);
        }
    };

    stage(0, 0);
    WAITV(0);
    __syncthreads();
    cvt_issue(0);                                 // overlaps tile 0 compute

    for (int t = 0; t < ntB; ++t) {
        if (t >= 4 && t <= 16 && (t & 3) == 0) cvt_flush4(t - 4);
        if (t >= 1 && t < 16) cvt_issue(t);
        const int buf = t & 1;
        const int kv0 = t * 64;
        if (t + 1 < ntB) stage(buf ^ 1, (t + 1) * 64);

        if (kv0 <= qw + 31) {                 // causal: this wave needs the tile
            // ---- QK^T swapped: sa[m][kb] = K_tile * Q^T -> C[kv][q] ----
            f32x4 sa[2][4] = {};
            #pragma unroll
            for (int kb = 0; kb < 4; ++kb) {
                bf16x8 kf[4];
                #pragma unroll
                for (int f = 0; f < 4; ++f)
                    kf[f] = *reinterpret_cast<const bf16x8*>(
                        &Klds[buf][(kb * 16 + r16) * 128 + (((f * 4 + g4) ^ (r16 & 7)) * 8)]);
                __builtin_amdgcn_s_setprio(1);
                #pragma unroll
                for (int m = 0; m < 2; ++m)
                    #pragma unroll
                    for (int f = 0; f < 4; ++f)
                        sa[m][kb] = __builtin_amdgcn_mfma_f32_16x16x32_bf16(
                            kf[f], qf[m][f], sa[m][kb], 0, 0, 0);
                __builtin_amdgcn_s_setprio(0);
            }
            // ---- causal mask: lane holds q = qw+m*16+r16, kv = kv0+kb*16+g4*4+r ----
            const bool needmask = (kv0 + 63 > qw);
            float sv[2][4][4];
            #pragma unroll
            for (int m = 0; m < 2; ++m)
                #pragma unroll
                for (int kb = 0; kb < 4; ++kb)
                    #pragma unroll
                    for (int r = 0; r < 4; ++r) {
                        float xx = sa[m][kb][r];
                        if (needmask) {
                            const int kvg = kv0 + kb * 16 + g4 * 4 + r;
                            const int qg  = qw + m * 16 + r16;
                            xx = (kvg > qg) ? -3e38f : xx;
                        }
                        sv[m][kb][r] = xx;
                    }
            // ---- per-q max: 15 in-lane ops + 2 shfl levels ----
            float rowm[2];
            #pragma unroll
            for (int m = 0; m < 2; ++m) {
                float a0 = fmaxf(fmaxf(sv[m][0][0], sv[m][0][1]), fmaxf(sv[m][0][2], sv[m][0][3]));
                float a1 = fmaxf(fmaxf(sv[m][1][0], sv[m][1][1]), fmaxf(sv[m][1][2], sv[m][1][3]));
                float a2 = fmaxf(fmaxf(sv[m][2][0], sv[m][2][1]), fmaxf(sv[m][2][2], sv[m][2][3]));
                float a3 = fmaxf(fmaxf(sv[m][3][0], sv[m][3][1]), fmaxf(sv[m][3][2], sv[m][3][3]));
                rowm[m] = fmaxf(fmaxf(a0, a1), fmaxf(a2, a3));
            }
            #pragma unroll
            for (int m = 0; m < 2; ++m) {
                rowm[m] = fmaxf(rowm[m], __shfl_xor(rowm[m], 16));
                rowm[m] = fmaxf(rowm[m], __shfl_xor(rowm[m], 32));
            }
            // ---- defer-max (T13, base-2 THR = 11.5 ~ e^8) ----
            const float gmax = fmaxf(rowm[0] - mr[0], rowm[1] - mr[1]);
            if (!__all(gmax <= 11.5f)) {
                float corr[2];
                #pragma unroll
                for (int m = 0; m < 2; ++m) {
                    const float mn = fmaxf(mr[m], rowm[m]);
                    corr[m] = exp2f(mr[m] - mn);
                    mr[m] = mn;
                    lr[m] *= corr[m];
                }
                #pragma unroll
                for (int m = 0; m < 2; ++m)
                    #pragma unroll
                    for (int r = 0; r < 4; ++r) {
                        const float co = __shfl(corr[m], (lane & 48) | (g4 * 4 + r));
                        #pragma unroll
                        for (int n = 0; n < 8; ++n) o[m][n][r] *= co;
                    }
            }
            // ---- P = exp2(S - m), row sums (in-lane + 2 shfl) ----
            float rs[2] = {0.f, 0.f};
            #pragma unroll
            for (int m = 0; m < 2; ++m)
                #pragma unroll
                for (int kb = 0; kb < 4; ++kb)
                    #pragma unroll
                    for (int r = 0; r < 4; ++r) {
                        const float pp = exp2f(sv[m][kb][r] - mr[m]);
                        sv[m][kb][r] = pp;
                        rs[m] += pp;
                    }
            #pragma unroll
            for (int m = 0; m < 2; ++m) {
                rs[m] += __shfl_xor(rs[m], 16);
                rs[m] += __shfl_xor(rs[m], 32);
                lr[m] += rs[m];
            }
            // ---- pack P pairs (cvt_pk) -> fragment-ordered Plds, 8 b64 writes ----
            #pragma unroll
            for (int m = 0; m < 2; ++m)
                #pragma unroll
                for (int kb = 0; kb < 4; ++kb) {
                    const unsigned w0 = cvt_pk_bf16(sv[m][kb][0], sv[m][kb][1]);
                    const unsigned w1 = cvt_pk_bf16(sv[m][kb][2], sv[m][kb][3]);
                    int wa = m * 2048 + ((kb * 2) + (g4 >> 1)) * 256 + r16 * 16 + (g4 & 1) * 8;
                    wa ^= (r16 >> 3) << 4;
                    *reinterpret_cast<unsigned long long*>(pw + wa) =
                        (unsigned long long)w0 | ((unsigned long long)w1 << 32);
                }
            asm volatile("s_waitcnt lgkmcnt(0)" ::: "memory");
            bf16x8 pa[2][2];
            #pragma unroll
            for (int m = 0; m < 2; ++m)
                #pragma unroll
                for (int kvs = 0; kvs < 2; ++kvs) {
                    int ra = m * 2048 + kvs * 1024 + lane * 16;
                    ra ^= (r16 >> 3) << 4;
                    pa[m][kvs] = *reinterpret_cast<const bf16x8*>(pw + ra);
                }
            // ---- PV: O[q][d] += P[q][kv] * Vt[d][kv] ----
            #pragma unroll
            for (int kvs = 0; kvs < 2; ++kvs)
                #pragma unroll
                for (int n = 0; n < 8; ++n) {
                    const bf16x8 vb = *reinterpret_cast<const bf16x8*>(
                        &Vlds[buf][(n * 16 + r16) * 64 + (((kvs * 4 + g4) ^ (r16 & 7)) * 8)]);
                    __builtin_amdgcn_s_setprio(1);
                    #pragma unroll
                    for (int m = 0; m < 2; ++m)
                        o[m][n] = __builtin_amdgcn_mfma_f32_16x16x32_bf16(
                            pa[m][kvs], vb, o[m][n], 0, 0, 0);
                    __builtin_amdgcn_s_setprio(0);
                }
        }

        WAITV(0);
        __syncthreads();
    }

    // ---- normalize (broadcast 1/lr to o-layout lanes) + write ----
    float inv[2];
    #pragma unroll
    for (int m = 0; m < 2; ++m) inv[m] = 1.0f / lr[m];
    #pragma unroll
    for (int m = 0; m < 2; ++m)
        #pragma unroll
        for (int r = 0; r < 4; ++r) {
            const float iv = __shfl(inv[m], (lane & 48) | (g4 * 4 + r));
            #pragma unroll
            for (int n = 0; n < 8; ++n)
                O[(size_t)(qw + m * 16 + g4 * 4 + r) * DD + h * HD2 + n * 16 + r16] =
                    f2b(o[m][n][r] * iv);
        }
}

// ---------------------------------------------------------------------------
extern "C" void kernel_launch(void* const* d_in, const int* in_sizes, int n_in,
                              void* d_out, int out_size, void* d_ws, size_t ws_size,
                              hipStream_t stream) {
    (void)in_sizes; (void)n_in; (void)out_size; (void)ws_size;
    const float* x  = (const float*)d_in[0];
    const float* wq = (const float*)d_in[1];
    const float* wk = (const float*)d_in[2];
    const float* wv = (const float*)d_in[3];
    const float* wo = (const float*)d_in[4];
    // d_in[5] = mask (causal tril; computed analytically in-kernel)
    const float* fc = (const float*)d_in[6];
    const float* fs = (const float*)d_in[7];
    float* out = (float*)d_out;

    unsigned short* ws = (unsigned short*)d_ws;
    const size_t M1 = 1024 * 1024;
    unsigned short* xb  = ws;              // 8M  (x bf16)
    unsigned short* wqb = ws + 8  * M1;    // 16M
    unsigned short* wkb = ws + 24 * M1;    // 4M
    unsigned short* wvb = ws + 28 * M1;    // 4M
    unsigned short* wob = ws + 32 * M1;    // 16M (written by attn side-job)
    unsigned short* qkv = ws + 48 * M1;    // 12M (S x 6144; q/k roped, v unused)
    unsigned short* vt  = ws + 60 * M1;    // 2M  (KVH x 128 x S; written by gemm_qkv)
    unsigned short* ob  = ws + 62 * M1;    // 8M  (S x 4096)

    cvt_all<<<2048, 256, 0, stream>>>(x, wq, wk, wv, ws);
    gemm_qkv<<<dim3(32, 8), 512, 0, stream>>>(xb, wqb, wkb, wvb, qkv, fc, fs, vt);
    attn_kernel<<<dim3(8, 32), 512, 0, stream>>>(qkv, vt, ob, wo, wob);
    gemm_out<<<dim3(16, 16), 512, 0, stream>>>(ob, wob, out);
}

// Round 19
// 274.891 us; speedup vs baseline: 1.0573x; 1.0573x over previous
//
#include <hip/hip_runtime.h>
#include <hip/hip_bf16.h>
#include <stdint.h>

// Problem constants
#define S2   2048
#define DD   4096
#define NH   32
#define NKVH 8
#define HD2  128
// qkv buffer row width: 4096 (q) + 1024 (k) + 1024 (v; written to Vt instead)
#define QKVW 6144

typedef __bf16 bf16x8 __attribute__((ext_vector_type(8)));
typedef float  f32x4  __attribute__((ext_vector_type(4)));
typedef unsigned short u16x8 __attribute__((ext_vector_type(8)));
typedef unsigned short u16x4 __attribute__((ext_vector_type(4)));

__device__ __forceinline__ unsigned short f2b(float f) {
    unsigned int u = __builtin_bit_cast(unsigned int, f);
    unsigned int r = (u + 0x7FFFu + ((u >> 16) & 1u)) >> 16;   // RNE
    return (unsigned short)r;
}
__device__ __forceinline__ float b2f(unsigned short h) {
    unsigned int u = ((unsigned int)h) << 16;
    return __builtin_bit_cast(float, u);
}
__device__ __forceinline__ unsigned cvt_pk_bf16(float a, float b) {
    unsigned r;
    asm("v_cvt_pk_bf16_f32 %0, %1, %2" : "=v"(r) : "v"(a), "v"(b));
    return r;   // lo16 = bf16(a), hi16 = bf16(b)
}

// global -> LDS direct copy, 16B per lane. LDS dest is wave-uniform base + lane*16.
__device__ __forceinline__ void gload_lds16(const void* g, void* lds) {
    __builtin_amdgcn_global_load_lds(
        (const __attribute__((address_space(1))) void*)(uintptr_t)g,
        (__attribute__((address_space(3))) void*)(uint32_t)(uintptr_t)lds,
        16, 0, 0);
}

// raw barrier (no vmcnt drain) + compiler memory fences so LDS ops don't cross
#define BAR() do { asm volatile("" ::: "memory"); \
                   __builtin_amdgcn_s_barrier();  \
                   asm volatile("" ::: "memory"); } while (0)
#define WAITV(n) asm volatile("s_waitcnt vmcnt(" #n ")" ::: "memory")

template<int N> __device__ __forceinline__ void waitv() {
    if      constexpr (N == 0)  WAITV(0);
    else if constexpr (N == 1)  WAITV(1);
    else if constexpr (N == 2)  WAITV(2);
    else if constexpr (N == 3)  WAITV(3);
    else if constexpr (N == 4)  WAITV(4);
    else if constexpr (N == 5)  WAITV(5);
    else if constexpr (N == 6)  WAITV(6);
    else if constexpr (N == 8)  WAITV(8);
}

// ---------------------------------------------------------------------------
// 1) fp32 -> bf16 conversion for x, wq, wk, wv (wo is converted inside attn)
// ---------------------------------------------------------------------------
__global__ void cvt_all(const float* __restrict__ x,  const float* __restrict__ wq,
                        const float* __restrict__ wk, const float* __restrict__ wv,
                        unsigned short* __restrict__ dst) {
    const long long NG = 8LL * 1024 * 1024;   // float4 groups (x 2M | wq 4M | wk 1M | wv 1M)
    const long long stride = (long long)gridDim.x * blockDim.x;
    for (long long g = (long long)blockIdx.x * blockDim.x + threadIdx.x; g < NG; g += stride) {
        const float* src; long long off;
        if      (g < 2LL*1024*1024) { src = x;  off = g; }
        else if (g < 6LL*1024*1024) { src = wq; off = g - 2LL*1024*1024; }
        else if (g < 7LL*1024*1024) { src = wk; off = g - 6LL*1024*1024; }
        else                        { src = wv; off = g - 7LL*1024*1024; }
        f32x4 v = *reinterpret_cast<const f32x4*>(src + off * 4);
        u16x4 o;
        o[0] = f2b(v[0]); o[1] = f2b(v[1]); o[2] = f2b(v[2]); o[3] = f2b(v[3]);
        *reinterpret_cast<u16x4*>(dst + g * 4) = o;
    }
}

// ---------------------------------------------------------------------------
// 2) QKV GEMM  qkv[2048 x 6144] = x * [wq|wk|wv]^T, with FUSED RoPE epilogue
//    and V written transposed to Vt. (r18, kept: saved ~8us vs rope_tv.)
//    2-barrier-per-tile schedule. BM=256, BN=192, BK=64, grid (32,8),
//    8 waves 4M x 2N.
// ---------------------------------------------------------------------------
__global__ __launch_bounds__(512) void gemm_qkv(
    const unsigned short* __restrict__ A,    // xb  [2048 x 4096]
    const unsigned short* __restrict__ B0,   // wq  [4096 x 4096]
    const unsigned short* __restrict__ B1,   // wk  [1024 x 4096]
    const unsigned short* __restrict__ B2,   // wv  [1024 x 4096]
    unsigned short* __restrict__ C,          // qkv [2048 x 6144]
    const float* __restrict__ fc,            // cos [2048 x 64]
    const float* __restrict__ fs,            // sin [2048 x 64]
    unsigned short* __restrict__ Vt)         // [8][128][2048]
{
    constexpr int K = 4096, BK = 64, NT = K / BK;
    __shared__ unsigned short As[2][256 * 64];   // 64 KB
    __shared__ unsigned short Bs[2][192 * 64];   // 48 KB

    const int bm = blockIdx.y, bn = blockIdx.x;  // (32, 8): lin%8 == bn%8
    const int tid = threadIdx.x;
    const int w = tid >> 6, lane = tid & 63;
    const int wr = w >> 1, wc = w & 1;           // 4M x 2N
    const int r16 = lane & 15, g4 = lane >> 4;

    const int bn0 = bn * 192;
    const unsigned short* Ap = A + (size_t)bm * 256 * K;

    const int lrow = lane >> 3;   // 0..7 (row within 8-row unit)
    const int lchk = lane & 7;    // 0..7 (16B chunk within 128B row)

    f32x4 acc[4][6] = {};
    bf16x8 af[4][2], b0[3][2], b1[3][2];

    auto browbase = [&](int rowg) -> const unsigned short* {
        if (rowg < 4096) return B0 + (size_t)rowg * K;
        if (rowg < 5120) return B1 + (size_t)(rowg - 4096) * K;
        return B2 + (size_t)(rowg - 5120) * K;
    };

    auto stageA = [&](int buf, int tt, int half) {
        #pragma unroll
        for (int i = 0; i < 2; ++i) {
            const int j = i * 8 + w;                               // unit 0..15
            const int row0 = (j >> 2) * 64 + half * 32 + (j & 3) * 8;
            const int row = row0 + lrow;
            gload_lds16(Ap + (size_t)row * K + tt * BK + ((lchk ^ (row & 7)) * 8),
                        &As[buf][row0 * 64]);
        }
    };
    auto stageB = [&](int buf, int tt, int half) {
        #pragma unroll
        for (int i = 0; i < 2; ++i) {
            const int j = (i == 0) ? w : (8 + (w & 3));            // unit 0..11
            const int row0 = (j < 6) ? (half * 48 + j * 8)
                                     : (96 + half * 48 + (j - 6) * 8);
            const int row = row0 + lrow;
            const unsigned short* src = browbase(bn0 + row0) + (size_t)lrow * K;
            gload_lds16(src + tt * BK + ((lchk ^ (row & 7)) * 8),
                        &Bs[buf][row0 * 64]);
        }
    };
    auto readA = [&](int buf, int mh) {
        #pragma unroll
        for (int m = 0; m < 2; ++m)
            #pragma unroll
            for (int kk = 0; kk < 2; ++kk) {
                const int row = wr * 64 + mh * 32 + m * 16 + r16;
                af[mh * 2 + m][kk] = *reinterpret_cast<const bf16x8*>(
                    &As[buf][row * 64 + (((kk * 4 + g4) ^ (row & 7)) * 8)]);
            }
    };
    auto readB = [&](int buf, int nh, bf16x8 (&br)[3][2]) {
        #pragma unroll
        for (int n = 0; n < 3; ++n)
            #pragma unroll
            for (int kk = 0; kk < 2; ++kk) {
                const int row = wc * 96 + nh * 48 + n * 16 + r16;
                br[n][kk] = *reinterpret_cast<const bf16x8*>(
                    &Bs[buf][row * 64 + (((kk * 4 + g4) ^ (row & 7)) * 8)]);
            }
    };
    auto mma = [&](bf16x8 (&br)[3][2], int nh) {   // all 4 m-frags x 3 n-frags
        __builtin_amdgcn_s_setprio(1);
        #pragma unroll
        for (int m = 0; m < 4; ++m)
            #pragma unroll
            for (int n = 0; n < 3; ++n)
                #pragma unroll
                for (int kk = 0; kk < 2; ++kk)
                    acc[m][nh * 3 + n] = __builtin_amdgcn_mfma_f32_16x16x32_bf16(
                        af[m][kk], br[n][kk], acc[m][nh * 3 + n], 0, 0, 0);
        __builtin_amdgcn_s_setprio(0);
    };

    // prologue: stage tile 0 fully, drain
    stageA(0, 0, 0); stageA(0, 0, 1); stageB(0, 0, 0); stageB(0, 0, 1);
    waitv<0>();
    BAR();

    for (int t = 0; t < NT - 1; ++t) {
        const int buf = t & 1;
        // ---- phase 0: all-m x n-half0 ----
        readA(buf, 0); readA(buf, 1); readB(buf, 0, b0);
        stageA(buf ^ 1, t + 1, 0); stageA(buf ^ 1, t + 1, 1); stageB(buf ^ 1, t + 1, 0);
        mma(b0, 0);
        waitv<6>();                 // lands B-h1(t); leaves A0',A1',B0'(t+1)
        BAR();
        // ---- phase 1: all-m x n-half1 ----
        readB(buf, 1, b1);
        stageB(buf ^ 1, t + 1, 1);
        mma(b1, 1);
        waitv<2>();                 // lands A0',A1',B0'(t+1); leaves B1'(t+1)
        BAR();
    }
    // ---- last tile (no staging) ----
    {
        const int buf = (NT - 1) & 1;
        readA(buf, 0); readA(buf, 1); readB(buf, 0, b0);
        mma(b0, 0);
        waitv<0>();                 // B-h1 landed (was left in flight)
        BAR();
        readB(buf, 1, b1);
        mma(b1, 1);
    }

    // ---- epilogue: fused RoPE (Q scaled) + V -> Vt transpose ----
    constexpr float QSCALE = 0.08838834764831845f * 1.4426950408889634f; // 1/sqrt(128)*log2(e)
    const int crow0 = bm * 256 + wr * 64;
    const int ccol0 = bn0 + wc * 96;
    #pragma unroll
    for (int m = 0; m < 4; ++m)
        #pragma unroll
        for (int n = 0; n < 6; ++n) {
            const int col = ccol0 + n * 16 + r16;
            if (col < 5120) {                          // Q or K: rope (wave-uniform branch)
                const int i0 = (col & 127) >> 1;
                const float post = (col < 4096) ? QSCALE : 1.0f;
                const bool ev = (col & 1) == 0;
                #pragma unroll
                for (int r = 0; r < 4; ++r) {
                    const int row = crow0 + m * 16 + g4 * 4 + r;
                    const float v  = acc[m][n][r];
                    const float pv = __shfl_xor(v, 1);     // partner column value
                    const float cc = fc[row * 64 + i0];
                    const float ss = fs[row * 64 + i0];
                    const float ov = ev ? (v * cc - pv * ss) : (pv * ss + v * cc);
                    C[(size_t)row * QKVW + col] = f2b(ov * post);
                }
            } else {                                   // V: transposed into Vt
                const int dl  = col - 5120;            // 0..1023
                const int kvh = dl >> 7, d = dl & 127;
                const int row0 = crow0 + m * 16 + g4 * 4;
                u16x4 vv;
                #pragma unroll
                for (int r = 0; r < 4; ++r) vv[r] = f2b(acc[m][n][r]);
                *reinterpret_cast<u16x4*>(
                    Vt + (size_t)kvh * HD2 * S2 + (size_t)d * S2 + row0) = vv;
            }
        }
}

// ---------------------------------------------------------------------------
// 2b) O-proj GEMM  out[2048 x 4096] = ob * wo^T.  (r17 2-barrier, unchanged)
// ---------------------------------------------------------------------------
__global__ __launch_bounds__(512) void gemm_out(
    const unsigned short* __restrict__ A,   // ob  [2048 x 4096] bf16
    const unsigned short* __restrict__ B,   // wob [4096 x 4096] bf16
    float* __restrict__ C)                  // out [2048 x 4096] f32
{
    constexpr int K = 4096, BK = 64, NT = K / BK;
    __shared__ unsigned short As[2][128 * 64];   // 32 KB
    __shared__ unsigned short Bs[2][256 * 64];   // 64 KB

    const int bm = blockIdx.y, bn = blockIdx.x;  // (16, 16): lin%8 == bn%8
    const int tid = threadIdx.x;
    const int w = tid >> 6, lane = tid & 63;
    const int wr = w >> 2, wc = w & 3;           // 2M x 4N
    const int r16 = lane & 15, g4 = lane >> 4;

    const unsigned short* Ap = A + (size_t)bm * 128 * K;
    const unsigned short* Bp = B + (size_t)bn * 256 * K;

    const int lrow = lane >> 3;
    const int lchk = lane & 7;

    f32x4 acc[4][4] = {};
    bf16x8 af[4][2], b0[2][2], b1[2][2];

    auto stageA = [&](int buf, int tt, int half) {
        const int j = w;                                           // unit 0..7
        const int row0 = (j >> 2) * 64 + half * 32 + (j & 3) * 8;
        const int row = row0 + lrow;
        gload_lds16(Ap + (size_t)row * K + tt * BK + ((lchk ^ (row & 7)) * 8),
                    &As[buf][row0 * 64]);
    };
    auto stageB = [&](int buf, int tt, int half) {
        #pragma unroll
        for (int i = 0; i < 2; ++i) {
            const int j = i * 8 + w;                               // unit 0..15
            const int row0 = (j >> 2) * 64 + half * 32 + (j & 3) * 8;
            const int row = row0 + lrow;
            gload_lds16(Bp + (size_t)row * K + tt * BK + ((lchk ^ (row & 7)) * 8),
                        &Bs[buf][row0 * 64]);
        }
    };
    auto readA = [&](int buf, int mh) {
        #pragma unroll
        for (int m = 0; m < 2; ++m)
            #pragma unroll
            for (int kk = 0; kk < 2; ++kk) {
                const int row = wr * 64 + mh * 32 + m * 16 + r16;
                af[mh * 2 + m][kk] = *reinterpret_cast<const bf16x8*>(
                    &As[buf][row * 64 + (((kk * 4 + g4) ^ (row & 7)) * 8)]);
            }
    };
    auto readB = [&](int buf, int nh, bf16x8 (&br)[2][2]) {
        #pragma unroll
        for (int n = 0; n < 2; ++n)
            #pragma unroll
            for (int kk = 0; kk < 2; ++kk) {
                const int row = wc * 64 + nh * 32 + n * 16 + r16;
                br[n][kk] = *reinterpret_cast<const bf16x8*>(
                    &Bs[buf][row * 64 + (((kk * 4 + g4) ^ (row & 7)) * 8)]);
            }
    };
    auto mma = [&](bf16x8 (&br)[2][2], int nh) {   // all 4 m-frags x 2 n-frags
        __builtin_amdgcn_s_setprio(1);
        #pragma unroll
        for (int m = 0; m < 4; ++m)
            #pragma unroll
            for (int n = 0; n < 2; ++n)
                #pragma unroll
                for (int kk = 0; kk < 2; ++kk)
                    acc[m][nh * 2 + n] = __builtin_amdgcn_mfma_f32_16x16x32_bf16(
                        af[m][kk], br[n][kk], acc[m][nh * 2 + n], 0, 0, 0);
        __builtin_amdgcn_s_setprio(0);
    };

    stageA(0, 0, 0); stageA(0, 0, 1); stageB(0, 0, 0); stageB(0, 0, 1);
    waitv<0>();
    BAR();

    for (int t = 0; t < NT - 1; ++t) {
        const int buf = t & 1;
        // ---- phase 0 ----
        readA(buf, 0); readA(buf, 1); readB(buf, 0, b0);
        stageA(buf ^ 1, t + 1, 0); stageA(buf ^ 1, t + 1, 1); stageB(buf ^ 1, t + 1, 0);
        mma(b0, 0);
        waitv<4>();                 // lands B-h1(t); leaves A0',A1',B0'(t+1)
        BAR();
        // ---- phase 1 ----
        readB(buf, 1, b1);
        stageB(buf ^ 1, t + 1, 1);
        mma(b1, 1);
        waitv<2>();                 // lands A0',A1',B0'(t+1); leaves B1'(t+1)
        BAR();
    }
    {
        const int buf = (NT - 1) & 1;
        readA(buf, 0); readA(buf, 1); readB(buf, 0, b0);
        mma(b0, 0);
        waitv<0>();
        BAR();
        readB(buf, 1, b1);
        mma(b1, 1);
    }

    const size_t crow0 = (size_t)bm * 128 + wr * 64;
    const size_t ccol0 = (size_t)bn * 256 + wc * 64;
    #pragma unroll
    for (int m = 0; m < 4; ++m)
        #pragma unroll
        for (int n = 0; n < 4; ++n)
            #pragma unroll
            for (int r = 0; r < 4; ++r)
                C[(crow0 + m * 16 + g4 * 4 + r) * DD + ccol0 + n * 16 + r16] = acc[m][n][r];
}

// ---------------------------------------------------------------------------
// 5) Flash attention (r12 body) + wo fp32->bf16 side-job, r17 per-tile flush
//    (measured 98 us; r18's batched flush regressed to 115 -> reverted).
//    16 batches x 2 f32x4; issue batch k at tile k; flush at tile k+1.
// ---------------------------------------------------------------------------
__global__ __launch_bounds__(512) void attn_kernel(const unsigned short* __restrict__ Qkv,
                                                   const unsigned short* __restrict__ Vt,
                                                   unsigned short* __restrict__ O,
                                                   const float* __restrict__ wo_src,
                                                   unsigned short* __restrict__ wo_dst) {
    __shared__ unsigned short Klds[2][64 * 128];   // 32 KB
    __shared__ unsigned short Vlds[2][128 * 64];   // 32 KB
    __shared__ unsigned short Plds[8][2048];       // 32 KB (4 KB/wave, frag-ordered)

    const int kvh = blockIdx.x;                  // 0..7
    const int h   = kvh * 4 + (blockIdx.y & 3);
    const int p   = blockIdx.y >> 2;             // pair id 0..7
    const int cB  = 8 + p, cS = 7 - p;           // complement chunks
    const int w = threadIdx.x >> 6, lane = threadIdx.x & 63;
    const int tid = threadIdx.x;
    const int r16 = lane & 15, g4 = lane >> 4;

    const int myc = (w < 4) ? cB : cS;
    const int qw  = myc * 128 + (w & 3) * 32;    // wave's first q row
    const int ntB = 2 * cB + 2;                  // tiles staged by this block (>= 18)

    const unsigned short* Kbase = Qkv + DD + kvh * HD2;      // + kv*QKVW + d
    const unsigned short* Vtb   = Vt + (size_t)kvh * HD2 * S2;
    char* pw = (char*)(&Plds[w][0]);             // wave's 4KB P region

    // wo conversion side-job: block blk covers 16384 f32x4 groups,
    // 16 batches x (2 f32x4 per thread), issue at tile k, flush at k+1.
    const int blk = blockIdx.y * 8 + blockIdx.x;           // 0..255
    const f32x4* wo4 = (const f32x4*)wo_src;
    const int cb4 = blk * 16384 + tid;
    f32x4 cbuf[2];
    auto cvt_issue = [&](int k) {
        #pragma unroll
        for (int i = 0; i < 2; ++i)
            cbuf[i] = wo4[cb4 + k * 1024 + i * 512];
    };
    auto cvt_flush = [&](int k) {
        #pragma unroll
        for (int i = 0; i < 2; ++i) {
            u16x4 ov;
            ov[0] = f2b(cbuf[i][0]); ov[1] = f2b(cbuf[i][1]);
            ov[2] = f2b(cbuf[i][2]); ov[3] = f2b(cbuf[i][3]);
            *reinterpret_cast<u16x4*>(wo_dst + ((size_t)(cb4 + k * 1024 + i * 512)) * 4) = ov;
        }
    };

    // staging lane constants
    const int krow_l = lane >> 4;      // row within 4-row segment
    const int kchunk = lane & 15;      // 16B chunk within 256B K row
    const int vd_l   = lane >> 3;      // d within 8-row segment
    const int vchunk = lane & 7;       // 16B chunk within 128B V row

    // Q fragments (B-frag of swapped QK^T): rows qw+m*16+r16, d-slices f*32+g4*8
    bf16x8 qf[2][4];
    #pragma unroll
    for (int m = 0; m < 2; ++m)
        #pragma unroll
        for (int f = 0; f < 4; ++f)
            qf[m][f] = *reinterpret_cast<const bf16x8*>(
                Qkv + (size_t)(qw + m * 16 + r16) * QKVW + h * HD2 + f * 32 + g4 * 8);

    f32x4 o[2][8] = {};
    float mr[2] = {-3e38f, -3e38f};   // running max (log2 units) for q = m*16+r16
    float lr[2] = {0.f, 0.f};

    auto stage = [&](int buf, int kv0) {
        #pragma unroll
        for (int i = 0; i < 2; ++i) {
            const int seg = i * 8 + w;                     // 0..15
            const int row = seg * 4 + krow_l;              // kv row 0..63
            gload_lds16(Kbase + (size_t)(kv0 + row) * QKVW + ((kchunk ^ (row & 7)) * 8),
                        &Klds[buf][seg * 512]);
        }
        #pragma unroll
        for (int i = 0; i < 2; ++i) {
            const int seg = i * 8 + w;
            const int d = seg * 8 + vd_l;                  // d row 0..127
            gload_lds16(Vtb + (size_t)d * S2 + kv0 + ((vchunk ^ (d & 7)) * 8),
                        &Vlds[buf][seg * 512]);
        }
    };

    stage(0, 0);
    WAITV(0);
    __syncthreads();
    cvt_issue(0);                                 // overlaps tile 0 compute

    for (int t = 0; t < ntB; ++t) {
        if (t >= 1 && t <= 16) {                  // batch t-1 drained at tile t-1 end
            cvt_flush(t - 1);
            if (t < 16) cvt_issue(t);
        }
        const int buf = t & 1;
        const int kv0 = t * 64;
        if (t + 1 < ntB) stage(buf ^ 1, (t + 1) * 64);

        if (kv0 <= qw + 31) {                 // causal: this wave needs the tile
            // ---- QK^T swapped: sa[m][kb] = K_tile * Q^T -> C[kv][q] ----
            f32x4 sa[2][4] = {};
            #pragma unroll
            for (int kb = 0; kb < 4; ++kb) {
                bf16x8 kf[4];
                #pragma unroll
                for (int f = 0; f < 4; ++f)
                    kf[f] = *reinterpret_cast<const bf16x8*>(
                        &Klds[buf][(kb * 16 + r16) * 128 + (((f * 4 + g4) ^ (r16 & 7)) * 8)]);
                __builtin_amdgcn_s_setprio(1);
                #pragma unroll
                for (int m = 0; m < 2; ++m)
                    #pragma unroll
                    for (int f = 0; f < 4; ++f)
                        sa[m][kb] = __builtin_amdgcn_mfma_f32_16x16x32_bf16(
                            kf[f], qf[m][f], sa[m][kb], 0, 0, 0);
                __builtin_amdgcn_s_setprio(0);
            }
            // ---- causal mask: lane holds q = qw+m*16+r16, kv = kv0+kb*16+g4*4+r ----
            const bool needmask = (kv0 + 63 > qw);
            float sv[2][4][4];
            #pragma unroll
            for (int m = 0; m < 2; ++m)
                #pragma unroll
                for (int kb = 0; kb < 4; ++kb)
                    #pragma unroll
                    for (int r = 0; r < 4; ++r) {
                        float xx = sa[m][kb][r];
                        if (needmask) {
                            const int kvg = kv0 + kb * 16 + g4 * 4 + r;
                            const int qg  = qw + m * 16 + r16;
                            xx = (kvg > qg) ? -3e38f : xx;
                        }
                        sv[m][kb][r] = xx;
                    }
            // ---- per-q max: 15 in-lane ops + 2 shfl levels ----
            float rowm[2];
            #pragma unroll
            for (int m = 0; m < 2; ++m) {
                float a0 = fmaxf(fmaxf(sv[m][0][0], sv[m][0][1]), fmaxf(sv[m][0][2], sv[m][0][3]));
                float a1 = fmaxf(fmaxf(sv[m][1][0], sv[m][1][1]), fmaxf(sv[m][1][2], sv[m][1][3]));
                float a2 = fmaxf(fmaxf(sv[m][2][0], sv[m][2][1]), fmaxf(sv[m][2][2], sv[m][2][3]));
                float a3 = fmaxf(fmaxf(sv[m][3][0], sv[m][3][1]), fmaxf(sv[m][3][2], sv[m][3][3]));
                rowm[m] = fmaxf(fmaxf(a0, a1), fmaxf(a2, a3));
            }
            #pragma unroll
            for (int m = 0; m < 2; ++m) {
                rowm[m] = fmaxf(rowm[m], __shfl_xor(rowm[m], 16));
                rowm[m] = fmaxf(rowm[m], __shfl_xor(rowm[m], 32));
            }
            // ---- defer-max (T13, base-2 THR = 11.5 ~ e^8) ----
            const float gmax = fmaxf(rowm[0] - mr[0], rowm[1] - mr[1]);
            if (!__all(gmax <= 11.5f)) {
                float corr[2];
                #pragma unroll
                for (int m = 0; m < 2; ++m) {
                    const float mn = fmaxf(mr[m], rowm[m]);
                    corr[m] = exp2f(mr[m] - mn);
                    mr[m] = mn;
                    lr[m] *= corr[m];
                }
                #pragma unroll
                for (int m = 0; m < 2; ++m)
                    #pragma unroll
                    for (int r = 0; r < 4; ++r) {
                        const float co = __shfl(corr[m], (lane & 48) | (g4 * 4 + r));
                        #pragma unroll
                        for (int n = 0; n < 8; ++n) o[m][n][r] *= co;
                    }
            }
            // ---- P = exp2(S - m), row sums (in-lane + 2 shfl) ----
            float rs[2] = {0.f, 0.f};
            #pragma unroll
            for (int m = 0; m < 2; ++m)
                #pragma unroll
                for (int kb = 0; kb < 4; ++kb)
                    #pragma unroll
                    for (int r = 0; r < 4; ++r) {
                        const float pp = exp2f(sv[m][kb][r] - mr[m]);
                        sv[m][kb][r] = pp;
                        rs[m] += pp;
                    }
            #pragma unroll
            for (int m = 0; m < 2; ++m) {
                rs[m] += __shfl_xor(rs[m], 16);
                rs[m] += __shfl_xor(rs[m], 32);
                lr[m] += rs[m];
            }
            // ---- pack P pairs (cvt_pk) -> fragment-ordered Plds, 8 b64 writes ----
            #pragma unroll
            for (int m = 0; m < 2; ++m)
                #pragma unroll
                for (int kb = 0; kb < 4; ++kb) {
                    const unsigned w0 = cvt_pk_bf16(sv[m][kb][0], sv[m][kb][1]);
                    const unsigned w1 = cvt_pk_bf16(sv[m][kb][2], sv[m][kb][3]);
                    int wa = m * 2048 + ((kb * 2) + (g4 >> 1)) * 256 + r16 * 16 + (g4 & 1) * 8;
                    wa ^= (r16 >> 3) << 4;
                    *reinterpret_cast<unsigned long long*>(pw + wa) =
                        (unsigned long long)w0 | ((unsigned long long)w1 << 32);
                }
            asm volatile("s_waitcnt lgkmcnt(0)" ::: "memory");
            bf16x8 pa[2][2];
            #pragma unroll
            for (int m = 0; m < 2; ++m)
                #pragma unroll
                for (int kvs = 0; kvs < 2; ++kvs) {
                    int ra = m * 2048 + kvs * 1024 + lane * 16;
                    ra ^= (r16 >> 3) << 4;
                    pa[m][kvs] = *reinterpret_cast<const bf16x8*>(pw + ra);
                }
            // ---- PV: O[q][d] += P[q][kv] * Vt[d][kv] ----
            #pragma unroll
            for (int kvs = 0; kvs < 2; ++kvs)
                #pragma unroll
                for (int n = 0; n < 8; ++n) {
                    const bf16x8 vb = *reinterpret_cast<const bf16x8*>(
                        &Vlds[buf][(n * 16 + r16) * 64 + (((kvs * 4 + g4) ^ (r16 & 7)) * 8)]);
                    __builtin_amdgcn_s_setprio(1);
                    #pragma unroll
                    for (int m = 0; m < 2; ++m)
                        o[m][n] = __builtin_amdgcn_mfma_f32_16x16x32_bf16(
                            pa[m][kvs], vb, o[m][n], 0, 0, 0);
                    __builtin_amdgcn_s_setprio(0);
                }
        }

        WAITV(0);
        __syncthreads();
    }

    // ---- normalize (broadcast 1/lr to o-layout lanes) + write ----
    float inv[2];
    #pragma unroll
    for (int m = 0; m < 2; ++m) inv[m] = 1.0f / lr[m];
    #pragma unroll
    for (int m = 0; m < 2; ++m)
        #pragma unroll
        for (int r = 0; r < 4; ++r) {
            const float iv = __shfl(inv[m], (lane & 48) | (g4 * 4 + r));
            #pragma unroll
            for (int n = 0; n < 8; ++n)
                O[(size_t)(qw + m * 16 + g4 * 4 + r) * DD + h * HD2 + n * 16 + r16] =
                    f2b(o[m][n][r] * iv);
        }
}

// ---------------------------------------------------------------------------
extern "C" void kernel_launch(void* const* d_in, const int* in_sizes, int n_in,
                              void* d_out, int out_size, void* d_ws, size_t ws_size,
                              hipStream_t stream) {
    (void)in_sizes; (void)n_in; (void)out_size; (void)ws_size;
    const float* x  = (const float*)d_in[0];
    const float* wq = (const float*)d_in[1];
    const float* wk = (const float*)d_in[2];
    const float* wv = (const float*)d_in[3];
    const float* wo = (const float*)d_in[4];
    // d_in[5] = mask (causal tril; computed analytically in-kernel)
    const float* fc = (const float*)d_in[6];
    const float* fs = (const float*)d_in[7];
    float* out = (float*)d_out;

    unsigned short* ws = (unsigned short*)d_ws;
    const size_t M1 = 1024 * 1024;
    unsigned short* xb  = ws;              // 8M  (x bf16)
    unsigned short* wqb = ws + 8  * M1;    // 16M
    unsigned short* wkb = ws + 24 * M1;    // 4M
    unsigned short* wvb = ws + 28 * M1;    // 4M
    unsigned short* wob = ws + 32 * M1;    // 16M (written by attn side-job)
    unsigned short* qkv = ws + 48 * M1;    // 12M (S x 6144; q/k roped, v unused)
    unsigned short* vt  = ws + 60 * M1;    // 2M  (KVH x 128 x S; written by gemm_qkv)
    unsigned short* ob  = ws + 62 * M1;    // 8M  (S x 4096)

    cvt_all<<<2048, 256, 0, stream>>>(x, wq, wk, wv, ws);
    gemm_qkv<<<dim3(32, 8), 512, 0, stream>>>(xb, wqb, wkb, wvb, qkv, fc, fs, vt);
    attn_kernel<<<dim3(8, 32), 512, 0, stream>>>(qkv, vt, ob, wo, wob);
    gemm_out<<<dim3(16, 16), 512, 0, stream>>>(ob, wob, out);
}